// Round 11
// baseline (146.441 us; speedup 1.0000x reference)
//
#include <hip/hip_runtime.h>
#include <hip/hip_bf16.h>
#include <hip/hip_cooperative_groups.h>

namespace cg = cooperative_groups;

// Problem constants
#define B_  16
#define S1_ 128
#define S2_ 256
#define H_  256
#define HM_ 512
#define QB  4    // q-rows per attn block-job
#define ESTR 520 // proj LDS row stride in halves

typedef _Float16 hf2 __attribute__((ext_vector_type(2)));
typedef _Float16 hf4 __attribute__((ext_vector_type(4)));
typedef _Float16 hf8 __attribute__((ext_vector_type(8)));
typedef float    f32x4 __attribute__((ext_vector_type(4)));

static __device__ inline hf2 u2h(unsigned u) {
    union { unsigned u; hf2 h; } x; x.u = u; return x.h;
}

static __device__ inline float dot2(hf2 a, hf2 b, float c) {
#if __has_builtin(__builtin_amdgcn_fdot2)
    return __builtin_amdgcn_fdot2(a, b, c, false);
#else
    asm("v_dot2_f32_f16 %0, %1, %2, %0" : "+v"(c) : "v"(a), "v"(b));
    return c;
#endif
}

struct AttnS {
    _Float16 qp_h[QB][HM_];     // 4 KB
    _Float16 w2_h[HM_];         // 1 KB
    float    Ap[2][QB][S2_];    // 8 KB
    float4   opart[8][QB][64];  // 32 KB
    float    rA_s[QB];
    float    qm_s[QB];
    float    km_s[S2_];
};
union SMemU {
    AttnS    a;
    _Float16 es[16 * ESTR];     // 16.6 KB proj C/X tile
};

// ---------------------------------------------------------------------------
// fused: one cooperative dispatch, 512 blocks x 512 threads.
//  phase 0: WB = frag-order fp16 repack of W1 (64 jobs/block)
//  phase 1: proj (blocks 0..383): QPh / KPTh via MFMA, coalesced epilogue
//  phase 2: attn (all 512 blocks) — logic identical to r10
// ---------------------------------------------------------------------------
__global__ __launch_bounds__(512, 4) void fused_kernel(
    const float* __restrict__ query,
    const float* __restrict__ key,
    const float* __restrict__ value,
    const float* __restrict__ q_mask,
    const float* __restrict__ k_mask,
    const float* __restrict__ W1,
    const float* __restrict__ b1,
    const float* __restrict__ W2,
    const float* __restrict__ b2,
    float* __restrict__ out,
    _Float16* __restrict__ QPh,    // [2048][512]
    _Float16* __restrict__ KPTh,   // [16][64][256][8]
    _Float16* __restrict__ WB)     // frag-order W
{
    cg::grid_group grid = cg::this_grid();
    __shared__ SMemU sm;

    const int t   = threadIdx.x;
    const int blk = blockIdx.x;

    // ---------------- phase 0: cvtWB (spread over all blocks) ----------------
    if (t < 64) {
        const int idx  = blk * 64 + t;            // 0..32767
        const int lane = idx & 63;
        const int nblk = (idx >> 6) & 31;
        const int kblk = idx >> 11;               // 0..15
        const int n    = nblk * 16 + (lane & 15);
        const int k0   = kblk * 32 + (lane >> 4) * 8;
        hf8 v;
#pragma unroll
        for (int j = 0; j < 8; ++j)
            v[j] = (_Float16)W1[(size_t)(k0 + j) * HM_ + n];
        *(hf8*)(WB + (size_t)idx * 8) = v;
    }
    grid.sync();

    // ---------------- phase 1: proj (blocks 0..383) ----------------
    if (blk < 384) {
        const bool modeK = blk >= 128;
        const int m0  = (modeK ? blk - 128 : blk) * 16;
        const float* X = modeK ? key : query;
        const int kb  = modeK ? 8 : 0;

        // stage X tile (16 rows x 256 k), fp32 -> fp16
        {
            const int row = t >> 5, c8 = (t & 31) * 8;
            const float* xs = X + (size_t)(m0 + row) * H_ + c8;
            float4 xa = *(const float4*)xs;
            float4 xb = *(const float4*)(xs + 4);
            hf8 xh = { (_Float16)xa.x, (_Float16)xa.y, (_Float16)xa.z, (_Float16)xa.w,
                       (_Float16)xb.x, (_Float16)xb.y, (_Float16)xb.z, (_Float16)xb.w };
            *(hf8*)&sm.es[row * ESTR + c8] = xh;
        }
        __syncthreads();

        const int lane = t & 63, w = t >> 6;
        const int fr = lane & 15;
        const int fk = (lane >> 4) * 8;

        f32x4 acc[4] = {};
#pragma unroll
        for (int s = 0; s < 8; ++s) {
            hf8 a = *(const hf8*)&sm.es[fr * ESTR + s * 32 + fk];
            const _Float16* bp =
                WB + ((((size_t)(kb + s) * 32 + w * 4) * 64) + lane) * 8;
#pragma unroll
            for (int nf = 0; nf < 4; ++nf) {
                hf8 bv = *(const hf8*)(bp + (size_t)nf * 64 * 8);
                acc[nf] = __builtin_amdgcn_mfma_f32_16x16x32_f16(a, bv, acc[nf], 0, 0, 0);
            }
        }

        __syncthreads();   // X reads done; reuse es as C tile

        // scatter acc -> es[mlocal][n] (fp16, bias folded for K mode)
#pragma unroll
        for (int nf = 0; nf < 4; ++nf) {
            const int n = w * 64 + nf * 16 + fr;
            const float bv = modeK ? b1[n] : 0.f;
#pragma unroll
            for (int r = 0; r < 4; ++r) {
                const int ml = (lane >> 4) * 4 + r;
                sm.es[ml * ESTR + n] = (_Float16)(acc[nf][r] + bv);
            }
        }
        __syncthreads();

        if (!modeK) {
            // QPh: 16 rows x 64 uint4 = 1024, 2 per thread
#pragma unroll
            for (int p = 0; p < 2; ++p) {
                const int idx = t + p * 512;
                const int row = idx >> 6, c8 = (idx & 63) * 8;
                *(uint4*)(QPh + (size_t)(m0 + row) * HM_ + c8) =
                    *(const uint4*)&sm.es[row * ESTR + c8];
            }
        } else {
            const int bb = m0 >> 8, kbase = m0 & 255;
#pragma unroll
            for (int p = 0; p < 2; ++p) {
                const int idx = t + p * 512;
                const int h8 = idx >> 4, kl = idx & 15;
                *(uint4*)(KPTh + (((size_t)bb * 64 + h8) * 256 + kbase + kl) * 8) =
                    *(const uint4*)&sm.es[kl * ESTR + h8 * 8];
            }
        }
    }
    grid.sync();

    // ---------------- phase 2: attn (all 512 blocks) ----------------
    {
        const int k  = t & 255;
        const int hb = t >> 8;

        // XCD-aware swizzle
        const int orig = blk;                       // 0..511
        const int wg   = (orig & 7) * 64 + (orig >> 3);
        const int q0   = (wg & 31) * QB;
        const int b    = wg >> 5;

        // stage qp (fp16), w2 (cvt), masks
        if (t < 256) {
            const uint4* src = (const uint4*)(QPh + (size_t)(b * S1_ + q0) * HM_);
            ((uint4*)&sm.a.qp_h[0][0])[t] = src[t];
            sm.a.km_s[t] = k_mask[b * S2_ + t];
        } else if (t < 256 + 128) {
            const int i = t - 256;
            float4 wvv = ((const float4*)W2)[i];
            hf4 hv = { (_Float16)wvv.x, (_Float16)wvv.y,
                       (_Float16)wvv.z, (_Float16)wvv.w };
            *(hf4*)&sm.a.w2_h[i * 4] = hv;
        } else if (t < 256 + 128 + QB) {
            const int i = t - (256 + 128);
            sm.a.qm_s[i] = q_mask[b * S1_ + q0 + i];
        }
        __syncthreads();

        // phase 2a: score partials (32 chunks of 8 h)
        float accs[QB] = {0.f, 0.f, 0.f, 0.f};
        const uint4* kp8 = (const uint4*)KPTh + ((size_t)b * 64 + hb * 32) * S2_ + k;

        for (int c = 0; c < 32; ++c) {
            uint4 kvu = kp8[(size_t)c * S2_];
            const int hoff = hb * (HM_ / 2) + c * 8;
            uint4 w4u = *(const uint4*)&sm.a.w2_h[hoff];
            hf2 kv0 = u2h(kvu.x), kv1 = u2h(kvu.y), kv2 = u2h(kvu.z), kv3 = u2h(kvu.w);
            hf2 wv0 = u2h(w4u.x), wv1 = u2h(w4u.y), wv2 = u2h(w4u.z), wv3 = u2h(w4u.w);
            const hf2 zero = (hf2)(_Float16)0;
#pragma unroll
            for (int q = 0; q < QB; ++q) {
                uint4 qvu = *(const uint4*)&sm.a.qp_h[q][hoff];
                hf2 s;
                s = __builtin_elementwise_max(u2h(qvu.x) + kv0, zero);
                accs[q] = dot2(s, wv0, accs[q]);
                s = __builtin_elementwise_max(u2h(qvu.y) + kv1, zero);
                accs[q] = dot2(s, wv1, accs[q]);
                s = __builtin_elementwise_max(u2h(qvu.z) + kv2, zero);
                accs[q] = dot2(s, wv2, accs[q]);
                s = __builtin_elementwise_max(u2h(qvu.w) + kv3, zero);
                accs[q] = dot2(s, wv3, accs[q]);
            }
        }
#pragma unroll
        for (int q = 0; q < QB; ++q) sm.a.Ap[hb][q][k] = accs[q];
        __syncthreads();

        // phase 2b: combine halves, mask, exp
        {
            const float b2v = b2[0];
#pragma unroll
            for (int i = 0; i < 2; ++i) {
                const int idx = t + i * 512;
                const int q = idx >> 8, kk = idx & 255;
                float sc = sm.a.Ap[0][q][kk] + sm.a.Ap[1][q][kk] + b2v;
                sm.a.Ap[0][q][kk] =
                    (sm.a.qm_s[q] * sm.a.km_s[kk] == 0.f) ? 0.f : __expf(sc);
            }
        }
        __syncthreads();

        // row sums
        if (t < QB * 64) {
            const int q = t >> 6, lane = t & 63;
            float p = sm.a.Ap[0][q][lane] + sm.a.Ap[0][q][lane + 64] +
                      sm.a.Ap[0][q][lane + 128] + sm.a.Ap[0][q][lane + 192];
#pragma unroll
            for (int m = 32; m >= 1; m >>= 1) p += __shfl_xor(p, m, 64);
            if (lane == 0) sm.a.rA_s[q] = 1.0f / fmaxf(p, 2e-15f);
        }
        __syncthreads();

        // PV: wave w owns value rows [w*32, w*32+32) for all 4 q
        {
            const int w = t >> 6, lane = t & 63;
            const float4* vb = (const float4*)(value + (size_t)b * S2_ * H_)
                               + (size_t)(w * 32) * (H_ / 4) + lane;
            float4 o[QB];
#pragma unroll
            for (int q = 0; q < QB; ++q) o[q] = make_float4(0.f, 0.f, 0.f, 0.f);
#pragma unroll 4
            for (int kk = 0; kk < 32; ++kk) {
                float4 v = vb[(size_t)kk * (H_ / 4)];
#pragma unroll
                for (int q = 0; q < QB; ++q) {
                    float a = sm.a.Ap[0][q][w * 32 + kk];
                    o[q].x = fmaf(a, v.x, o[q].x); o[q].y = fmaf(a, v.y, o[q].y);
                    o[q].z = fmaf(a, v.z, o[q].z); o[q].w = fmaf(a, v.w, o[q].w);
                }
            }
#pragma unroll
            for (int q = 0; q < QB; ++q) sm.a.opart[w][q][lane] = o[q];
        }
        __syncthreads();

        // combine 8 partials, normalize, store
        if (t < QB * 64) {
            const int q = t >> 6, lane = t & 63;
            float4 s = make_float4(0.f, 0.f, 0.f, 0.f);
#pragma unroll
            for (int w = 0; w < 8; ++w) {
                float4 p = sm.a.opart[w][q][lane];
                s.x += p.x; s.y += p.y; s.z += p.z; s.w += p.w;
            }
            const float r = sm.a.rA_s[q];
            s.x *= r; s.y *= r; s.z *= r; s.w *= r;
            *(float4*)(out + (size_t)(b * S1_ + q0 + q) * H_ + lane * 4) = s;
        }
    }
}

extern "C" void kernel_launch(void* const* d_in, const int* in_sizes, int n_in,
                              void* d_out, int out_size, void* d_ws, size_t ws_size,
                              hipStream_t stream) {
    const float* query  = (const float*)d_in[0];  // [16,128,256]
    const float* key    = (const float*)d_in[1];  // [16,256,256]
    const float* value  = (const float*)d_in[2];  // [16,256,256]
    const float* q_mask = (const float*)d_in[3];  // [16,128]
    const float* k_mask = (const float*)d_in[4];  // [16,256]
    const float* W1     = (const float*)d_in[5];  // [512,512]
    const float* b1     = (const float*)d_in[6];  // [512]
    const float* W2     = (const float*)d_in[7];  // [512,1]
    const float* b2     = (const float*)d_in[8];  // [1]
    float*       out    = (float*)d_out;

    _Float16* QPh  = (_Float16*)d_ws;                  // [2048][512]      2 MB
    _Float16* KPTh = QPh  + (size_t)B_ * S1_ * HM_;    // [16][64][256][8] 4 MB
    _Float16* WB   = KPTh + (size_t)B_ * S2_ * HM_;    // frag-order W   0.5 MB

    void* args[] = {
        (void*)&query, (void*)&key, (void*)&value,
        (void*)&q_mask, (void*)&k_mask,
        (void*)&W1, (void*)&b1, (void*)&W2, (void*)&b2,
        (void*)&out, (void*)&QPh, (void*)&KPTh, (void*)&WB
    };
    hipLaunchCooperativeKernel((void*)fused_kernel, dim3(512), dim3(512),
                               args, 0, stream);
}